// Round 2
// baseline (1120.122 us; speedup 1.0000x reference)
//
#include <hip/hip_runtime.h>

// GCN layer: out = D^{-1/2} A D^{-1/2} X  (index == arange(N) => scatter is identity)
// N=100000, E=6400000, D=32.
// Round 2: CSR build on device + wave-per-row SpMM (no output atomics).

#define FEAT_D 32

// ====================== CSR path ======================

__global__ void count_kernel(const int* __restrict__ rows, int* __restrict__ counts, int E) {
    int i = blockIdx.x * blockDim.x + threadIdx.x;
    int stride = gridDim.x * blockDim.x;
    for (; i < E; i += stride) {
        atomicAdd(&counts[rows[i]], 1);
    }
}

// Single-block chunked Hillis-Steele exclusive scan over n ints -> offsets[0..n]
__global__ void scan_kernel(const int* __restrict__ counts, int* __restrict__ offsets, int n) {
    __shared__ int buf[1024];
    __shared__ int carry;
    int tid = threadIdx.x;
    if (tid == 0) carry = 0;
    __syncthreads();
    for (int base = 0; base < n; base += 1024) {
        int idx = base + tid;
        int v = (idx < n) ? counts[idx] : 0;
        buf[tid] = v;
        __syncthreads();
        for (int off = 1; off < 1024; off <<= 1) {
            int t = (tid >= off) ? buf[tid - off] : 0;
            __syncthreads();
            buf[tid] += t;
            __syncthreads();
        }
        int incl = buf[tid];
        int c = carry;
        if (idx < n) offsets[idx] = c + incl - v;   // exclusive
        __syncthreads();
        if (tid == 1023) carry = c + incl;
        __syncthreads();
    }
    if (tid == 0) offsets[n] = carry;
}

__global__ void scatter_kernel(const int* __restrict__ rows, const int* __restrict__ cols,
                               const float* __restrict__ vals,
                               int* __restrict__ cursor,
                               int* __restrict__ csr_col, float* __restrict__ csr_val, int E) {
    int i = blockIdx.x * blockDim.x + threadIdx.x;
    int stride = gridDim.x * blockDim.x;
    for (; i < E; i += stride) {
        int r = rows[i];
        int pos = atomicAdd(&cursor[r], 1);
        csr_col[pos] = cols[i];
        csr_val[pos] = vals[i];
    }
}

// one wave per row: rowsum via coalesced segment read + butterfly reduce
__global__ void dinv_csr_kernel(const int* __restrict__ offsets, const float* __restrict__ csr_val,
                                float* __restrict__ dinv, int n) {
    int wave = (blockIdx.x * blockDim.x + threadIdx.x) >> 6;
    int lane = threadIdx.x & 63;
    if (wave >= n) return;
    int beg = offsets[wave], end = offsets[wave + 1];
    float s = 0.0f;
    for (int i = beg + lane; i < end; i += 64) s += csr_val[i];
    for (int m = 32; m >= 1; m >>= 1) s += __shfl_xor(s, m, 64);
    if (lane == 0) dinv[wave] = (s > 0.0f) ? rsqrtf(s) : 0.0f;
}

// one wave per row: lanes = (edge parity p) x (dim d). Register accumulate, one store.
__global__ void spmm_csr_kernel(const int* __restrict__ offsets, const int* __restrict__ csr_col,
                                const float* __restrict__ csr_val, const float* __restrict__ dinv,
                                const float* __restrict__ feat, float* __restrict__ out, int n) {
    int wave = (blockIdx.x * blockDim.x + threadIdx.x) >> 6;
    int lane = threadIdx.x & 63;
    if (wave >= n) return;
    int r = wave;
    int beg = offsets[r], end = offsets[r + 1];
    int d = lane & 31;
    int p = lane >> 5;
    float acc = 0.0f;
    #pragma unroll 4
    for (int i = beg + p; i < end; i += 2) {
        int c = csr_col[i];
        float w = csr_val[i] * dinv[c];
        acc = fmaf(w, feat[(size_t)c * FEAT_D + d], acc);
    }
    acc += __shfl_xor(acc, 32, 64);
    if (p == 0) out[(size_t)r * FEAT_D + d] = dinv[r] * acc;
}

// ====================== fallback atomic path (ws too small) ======================

__global__ void degree_kernel(const int* __restrict__ rows, const float* __restrict__ vals,
                              float* __restrict__ rowsum, int E) {
    int i = blockIdx.x * blockDim.x + threadIdx.x;
    int stride = gridDim.x * blockDim.x;
    for (; i < E; i += stride) atomicAdd(&rowsum[rows[i]], vals[i]);
}

__global__ void dinv_kernel(const float* __restrict__ rowsum, float* __restrict__ dinv, int n) {
    int i = blockIdx.x * blockDim.x + threadIdx.x;
    if (i < n) {
        float r = rowsum[i];
        dinv[i] = (r > 0.0f) ? rsqrtf(r) : 0.0f;
    }
}

__global__ void spmm_kernel(const int* __restrict__ rows, const int* __restrict__ cols,
                            const float* __restrict__ vals, const float* __restrict__ dinv,
                            const float* __restrict__ feat, float* __restrict__ out, int E) {
    long long tid = (long long)blockIdx.x * blockDim.x + threadIdx.x;
    long long total = (long long)E * FEAT_D;
    long long stride = (long long)gridDim.x * blockDim.x;
    for (; tid < total; tid += stride) {
        int e = (int)(tid >> 5);
        int d = (int)(tid & 31);
        int r = rows[e];
        int c = cols[e];
        float w = dinv[r] * vals[e] * dinv[c];
        atomicAdd(&out[(long long)r * FEAT_D + d], w * feat[(long long)c * FEAT_D + d]);
    }
}

// ====================== launch ======================

extern "C" void kernel_launch(void* const* d_in, const int* in_sizes, int n_in,
                              void* d_out, int out_size, void* d_ws, size_t ws_size,
                              hipStream_t stream) {
    const float* features = (const float*)d_in[0];
    const int*   adj_rows = (const int*)d_in[1];
    const int*   adj_cols = (const int*)d_in[2];
    const float* adj_vals = (const float*)d_in[3];
    // d_in[4] = index == arange(N): identity scatter, unused.

    float* out = (float*)d_out;
    int E = in_sizes[1];
    int n = in_sizes[4];

    // ws layout: counts[n] | offsets[n+1] | cursor[n] | dinv[n] | csr_col[E] | csr_val[E]
    size_t need = ((size_t)4 * n + 1) * sizeof(int) + (size_t)E * 8;

    if (ws_size >= need) {
        int*   counts  = (int*)d_ws;
        int*   offsets = counts + n;
        int*   cursor  = offsets + n + 1;
        float* dinv    = (float*)(cursor + n);
        int*   csr_col = (int*)(dinv + n);
        float* csr_val = (float*)(csr_col + E);

        hipMemsetAsync(counts, 0, (size_t)n * sizeof(int), stream);

        int block = 256;
        int egrid = (E + block - 1) / block;
        if (egrid > 8192) egrid = 8192;

        count_kernel<<<egrid, block, 0, stream>>>(adj_rows, counts, E);
        scan_kernel<<<1, 1024, 0, stream>>>(counts, offsets, n);
        hipMemcpyAsync(cursor, offsets, (size_t)n * sizeof(int),
                       hipMemcpyDeviceToDevice, stream);
        scatter_kernel<<<egrid, block, 0, stream>>>(adj_rows, adj_cols, adj_vals,
                                                    cursor, csr_col, csr_val, E);

        int rows_per_block = block / 64;   // 4 waves per block, 1 row per wave
        int rgrid = (n + rows_per_block - 1) / rows_per_block;
        dinv_csr_kernel<<<rgrid, block, 0, stream>>>(offsets, csr_val, dinv, n);
        spmm_csr_kernel<<<rgrid, block, 0, stream>>>(offsets, csr_col, csr_val,
                                                     dinv, features, out, n);
    } else {
        // fallback: atomic path
        float* rowsum = (float*)d_ws;
        float* dinv   = rowsum + n;
        hipMemsetAsync(rowsum, 0, (size_t)n * sizeof(float), stream);
        hipMemsetAsync(out, 0, (size_t)out_size * sizeof(float), stream);
        int block = 256;
        int egrid = (E + block - 1) / block;
        if (egrid > 8192) egrid = 8192;
        degree_kernel<<<egrid, block, 0, stream>>>(adj_rows, adj_vals, rowsum, E);
        int ngrid = (n + block - 1) / block;
        dinv_kernel<<<ngrid, block, 0, stream>>>(rowsum, dinv, n);
        long long total = (long long)E * FEAT_D;
        long long gridl = (total + block - 1) / block;
        int grid = (gridl > 8192) ? 8192 : (int)gridl;
        spmm_kernel<<<grid, block, 0, stream>>>(adj_rows, adj_cols, adj_vals,
                                                dinv, features, out, E);
    }
}

// Round 3
// 921.143 us; speedup vs baseline: 1.2160x; 1.2160x over previous
//
#include <hip/hip_runtime.h>

// GCN layer: out = D^{-1/2} A D^{-1/2} X  (index == arange(N) => scatter is identity)
// N=100000, E=6400000, D=32.
// Round 3: packed int2 CSR entries (one 8B store/edge), parallel scan,
//          dinv from CSR stream (no float atomic histogram).

#define FEAT_D 32

// ---------- pass 1: degree count (int atomics, L2-resident 400KB) ----------
__global__ void count_kernel(const int* __restrict__ rows, int* __restrict__ counts, int E) {
    int i = blockIdx.x * blockDim.x + threadIdx.x;
    int stride = gridDim.x * blockDim.x;
    for (; i < E; i += stride) atomicAdd(&counts[rows[i]], 1);
}

// ---------- pass 2: parallel exclusive scan (3 small kernels) ----------
// K2a: per-block (1024 elems) reduce -> partials[b]
__global__ void scan_reduce(const int* __restrict__ counts, int* __restrict__ partials, int n) {
    __shared__ int tsum[256];
    int b = blockIdx.x, tid = threadIdx.x;
    int base = b * 1024 + tid * 4;
    int s = 0;
    #pragma unroll
    for (int j = 0; j < 4; ++j) s += (base + j < n) ? counts[base + j] : 0;
    tsum[tid] = s;
    __syncthreads();
    for (int off = 128; off >= 1; off >>= 1) {
        if (tid < off) tsum[tid] += tsum[tid + off];
        __syncthreads();
    }
    if (tid == 0) partials[b] = tsum[0];
}

// K2b: single block scans up to 1024 partials (exclusive), writes offsets[n]=total
__global__ void scan_partials(int* __restrict__ partials, int* __restrict__ offsets,
                              int nb, int n) {
    __shared__ int buf[1024];
    int tid = threadIdx.x;
    int v = (tid < nb) ? partials[tid] : 0;
    buf[tid] = v;
    __syncthreads();
    for (int off = 1; off < 1024; off <<= 1) {
        int t = (tid >= off) ? buf[tid - off] : 0;
        __syncthreads();
        buf[tid] += t;
        __syncthreads();
    }
    if (tid < nb) partials[tid] = buf[tid] - v;   // exclusive
    if (tid == nb - 1) offsets[n] = buf[tid];     // grand total
}

// K2c: per-block exclusive scan + add partial; writes offsets AND cursor
__global__ void scan_apply(const int* __restrict__ counts, const int* __restrict__ partials,
                           int* __restrict__ offsets, int* __restrict__ cursor, int n) {
    __shared__ int tsum[256];
    int b = blockIdx.x, tid = threadIdx.x;
    int base = b * 1024 + tid * 4;
    int v[4];
    int s = 0;
    #pragma unroll
    for (int j = 0; j < 4; ++j) { v[j] = (base + j < n) ? counts[base + j] : 0; s += v[j]; }
    tsum[tid] = s;
    __syncthreads();
    for (int off = 1; off < 256; off <<= 1) {
        int t = (tid >= off) ? tsum[tid - off] : 0;
        __syncthreads();
        tsum[tid] += t;
        __syncthreads();
    }
    int running = tsum[tid] - s + partials[b];
    #pragma unroll
    for (int j = 0; j < 4; ++j) {
        if (base + j < n) { offsets[base + j] = running; cursor[base + j] = running; }
        running += v[j];
    }
}

// ---------- pass 3: scatter packed (col, val) -> single 8B store per edge ----------
__global__ void scatter_kernel(const int* __restrict__ rows, const int* __restrict__ cols,
                               const float* __restrict__ vals,
                               int* __restrict__ cursor, int2* __restrict__ csr, int E) {
    int i = blockIdx.x * blockDim.x + threadIdx.x;
    int stride = gridDim.x * blockDim.x;
    for (; i < E; i += stride) {
        int r = rows[i];
        int pos = atomicAdd(&cursor[r], 1);
        csr[pos] = make_int2(cols[i], __float_as_int(vals[i]));
    }
}

// ---------- pass 4: dinv from CSR stream (wave per row) ----------
__global__ void dinv_csr_kernel(const int* __restrict__ offsets, const int2* __restrict__ csr,
                                float* __restrict__ dinv, int n) {
    int wave = (blockIdx.x * blockDim.x + threadIdx.x) >> 6;
    int lane = threadIdx.x & 63;
    if (wave >= n) return;
    int beg = offsets[wave], end = offsets[wave + 1];
    float s = 0.0f;
    for (int i = beg + lane; i < end; i += 64) s += __int_as_float(csr[i].y);
    for (int m = 32; m >= 1; m >>= 1) s += __shfl_xor(s, m, 64);
    if (lane == 0) dinv[wave] = (s > 0.0f) ? rsqrtf(s) : 0.0f;
}

// ---------- pass 5: SpMM, wave per row, register accumulate, no atomics ----------
__global__ void spmm_csr_kernel(const int* __restrict__ offsets, const int2* __restrict__ csr,
                                const float* __restrict__ dinv, const float* __restrict__ feat,
                                float* __restrict__ out, int n) {
    int wave = (blockIdx.x * blockDim.x + threadIdx.x) >> 6;
    int lane = threadIdx.x & 63;
    if (wave >= n) return;
    int r = wave;
    int beg = offsets[r], end = offsets[r + 1];
    int d = lane & 31;
    int p = lane >> 5;
    float acc = 0.0f;
    #pragma unroll 4
    for (int i = beg + p; i < end; i += 2) {
        int2 e = csr[i];                       // same addr within half-wave: broadcast
        int c = e.x;
        float w = __int_as_float(e.y) * dinv[c];
        acc = fmaf(w, feat[(size_t)c * FEAT_D + d], acc);
    }
    acc += __shfl_xor(acc, 32, 64);
    if (p == 0) out[(size_t)r * FEAT_D + d] = dinv[r] * acc;
}

// ---------- fallback atomic path (ws too small) ----------
__global__ void degree_kernel(const int* __restrict__ rows, const float* __restrict__ vals,
                              float* __restrict__ rowsum, int E) {
    int i = blockIdx.x * blockDim.x + threadIdx.x;
    int stride = gridDim.x * blockDim.x;
    for (; i < E; i += stride) atomicAdd(&rowsum[rows[i]], vals[i]);
}
__global__ void dinv_kernel(const float* __restrict__ rowsum, float* __restrict__ dinv, int n) {
    int i = blockIdx.x * blockDim.x + threadIdx.x;
    if (i < n) { float r = rowsum[i]; dinv[i] = (r > 0.0f) ? rsqrtf(r) : 0.0f; }
}
__global__ void spmm_kernel(const int* __restrict__ rows, const int* __restrict__ cols,
                            const float* __restrict__ vals, const float* __restrict__ dinv,
                            const float* __restrict__ feat, float* __restrict__ out, int E) {
    long long tid = (long long)blockIdx.x * blockDim.x + threadIdx.x;
    long long total = (long long)E * FEAT_D;
    long long stride = (long long)gridDim.x * blockDim.x;
    for (; tid < total; tid += stride) {
        int e = (int)(tid >> 5);
        int d = (int)(tid & 31);
        int r = rows[e];
        int c = cols[e];
        float w = dinv[r] * vals[e] * dinv[c];
        atomicAdd(&out[(long long)r * FEAT_D + d], w * feat[(long long)c * FEAT_D + d]);
    }
}

// ---------- launch ----------
extern "C" void kernel_launch(void* const* d_in, const int* in_sizes, int n_in,
                              void* d_out, int out_size, void* d_ws, size_t ws_size,
                              hipStream_t stream) {
    const float* features = (const float*)d_in[0];
    const int*   adj_rows = (const int*)d_in[1];
    const int*   adj_cols = (const int*)d_in[2];
    const float* adj_vals = (const float*)d_in[3];
    // d_in[4] = index == arange(N): identity scatter, unused.

    float* out = (float*)d_out;
    int E = in_sizes[1];
    int n = in_sizes[4];
    int nb = (n + 1023) / 1024;   // scan blocks (must be <= 1024)

    // ws layout: counts[n] | offsets[n+1] | cursor[n] | partials[nb] | dinv[n] | pad | csr int2[E]
    size_t ints_before = (size_t)3 * n + 1 + nb + n;
    size_t csr_off = ((ints_before * 4 + 15) / 16) * 16;            // 16B align
    size_t need = csr_off + (size_t)E * sizeof(int2);

    if (ws_size >= need && nb <= 1024) {
        int*   counts   = (int*)d_ws;
        int*   offsets  = counts + n;
        int*   cursor   = offsets + n + 1;
        int*   partials = cursor + n;
        float* dinv     = (float*)(partials + nb);
        int2*  csr      = (int2*)((char*)d_ws + csr_off);

        hipMemsetAsync(counts, 0, (size_t)n * sizeof(int), stream);

        int block = 256;
        int egrid = (E + block - 1) / block;
        if (egrid > 8192) egrid = 8192;

        count_kernel<<<egrid, block, 0, stream>>>(adj_rows, counts, E);
        scan_reduce<<<nb, 256, 0, stream>>>(counts, partials, n);
        scan_partials<<<1, 1024, 0, stream>>>(partials, offsets, nb, n);
        scan_apply<<<nb, 256, 0, stream>>>(counts, partials, offsets, cursor, n);
        scatter_kernel<<<egrid, block, 0, stream>>>(adj_rows, adj_cols, adj_vals,
                                                    cursor, csr, E);

        int rows_per_block = block / 64;   // 4 waves/block, 1 row/wave
        int rgrid = (n + rows_per_block - 1) / rows_per_block;
        dinv_csr_kernel<<<rgrid, block, 0, stream>>>(offsets, csr, dinv, n);
        spmm_csr_kernel<<<rgrid, block, 0, stream>>>(offsets, csr, dinv, features, out, n);
    } else {
        // fallback: atomic path
        float* rowsum = (float*)d_ws;
        float* dinv   = rowsum + n;
        hipMemsetAsync(rowsum, 0, (size_t)n * sizeof(float), stream);
        hipMemsetAsync(out, 0, (size_t)out_size * sizeof(float), stream);
        int block = 256;
        int egrid = (E + block - 1) / block;
        if (egrid > 8192) egrid = 8192;
        degree_kernel<<<egrid, block, 0, stream>>>(adj_rows, adj_vals, rowsum, E);
        int ngrid = (n + block - 1) / block;
        dinv_kernel<<<ngrid, block, 0, stream>>>(rowsum, dinv, n);
        long long total = (long long)E * FEAT_D;
        long long gridl = (total + block - 1) / block;
        int grid = (gridl > 8192) ? 8192 : (int)gridl;
        spmm_kernel<<<grid, block, 0, stream>>>(adj_rows, adj_cols, adj_vals,
                                                dinv, features, out, E);
    }
}